// Round 7
// baseline (6364.494 us; speedup 1.0000x reference)
//
#include <hip/hip_runtime.h>
#include <cstdint>

// ---------------------------------------------------------------------------
// SparseAttention — R7: QK^T streams K from L2 into registers (NO barriers,
// no LDS staging in the hot loop — R6 counters showed the 64-barrier pipeline
// at 1 block/CU was the limiter, not FMA). P stored as f32 row-pair layout
// (float2 LDS reads, no f16 cvt in PV). Selection semantics bit-identical to
// R3..R6 (d-ascending fp64 FMA order preserved; absmax must stay 2.563e-3).
// ---------------------------------------------------------------------------

#define BB 2
#define NN 2048
#define CC 1024
#define HH 16
#define HD 64
#define KSP 204

__device__ __forceinline__ unsigned long long mono64(double s) {
  long long bb = __double_as_longlong(s);
  return (unsigned long long)bb ^
         ((bb < 0) ? 0xFFFFFFFFFFFFFFFFull : 0x8000000000000000ull);
}

// ---------------------------------------------------------------------------
// Kernel 1: Q,K projection in fp64. 64x64 tile, 4x4 micro. Cols [0,2048).
// ---------------------------------------------------------------------------
__global__ __launch_bounds__(256) void qk_gemm_f64(
    const float* __restrict__ x, const float* __restrict__ w,
    const float* __restrict__ bqkv, double* __restrict__ Qd,
    double* __restrict__ Kd) {
  __shared__ double As[16][64];  // [k][m]
  __shared__ double Bs[16][64];  // [k][n]
  const int tid = threadIdx.x;
  const int tx = tid & 15, ty = tid >> 4;
  const int colbase = blockIdx.x * 64, rowbase = blockIdx.y * 64;

  double acc[4][4] = {};

  const int sr = tid >> 2, sc = (tid & 3) * 4;
  const int bk = tid >> 4, bn = (tid & 15) * 4;

  for (int kt = 0; kt < 64; ++kt) {
    const int k0 = kt * 16;
    const float4 av = *(const float4*)(x + (size_t)(rowbase + sr) * 1024 + k0 + sc);
    const float4 bv = *(const float4*)(w + (size_t)(k0 + bk) * 3072 + colbase + bn);
    __syncthreads();
    As[sc + 0][sr] = (double)av.x;
    As[sc + 1][sr] = (double)av.y;
    As[sc + 2][sr] = (double)av.z;
    As[sc + 3][sr] = (double)av.w;
    Bs[bk][bn + 0] = (double)bv.x;
    Bs[bk][bn + 1] = (double)bv.y;
    Bs[bk][bn + 2] = (double)bv.z;
    Bs[bk][bn + 3] = (double)bv.w;
    __syncthreads();
#pragma unroll
    for (int k = 0; k < 16; ++k) {
      double a[4], b[4];
#pragma unroll
      for (int i = 0; i < 4; ++i) a[i] = As[k][ty + 16 * i];
#pragma unroll
      for (int j = 0; j < 4; ++j) b[j] = Bs[k][tx + 16 * j];
#pragma unroll
      for (int i = 0; i < 4; ++i)
#pragma unroll
        for (int j = 0; j < 4; ++j) acc[i][j] = fma(a[i], b[j], acc[i][j]);
    }
  }

  const int region = colbase >> 10;  // 0=Q 1=K (uniform per block)
#pragma unroll
  for (int j = 0; j < 4; ++j) {
    const int col = colbase + tx + 16 * j;
    const double bias = (double)bqkv[col];
    const int h = (col & 1023) >> 6, d = col & 63;
#pragma unroll
    for (int i = 0; i < 4; ++i) {
      const int row = rowbase + ty + 16 * i;
      const int b = row >> 11, n = row & 2047;
      const size_t o = ((size_t)((b * HH + h) * HD + d)) * NN + n;
      const double v = acc[i][j] + bias;
      if (region == 0)
        Qd[o] = v * 0.125;
      else
        Kd[o] = v;
    }
  }
}

// ---------------------------------------------------------------------------
// Kernel 1b: V projection in fp32. Cols [2048,3072) of w_qkv.
// ---------------------------------------------------------------------------
__global__ __launch_bounds__(256) void v_gemm_f32(
    const float* __restrict__ x, const float* __restrict__ w,
    const float* __restrict__ bqkv, float* __restrict__ Vf) {
  __shared__ float As[16][64];
  __shared__ float Bs[16][64];
  const int tid = threadIdx.x;
  const int tx = tid & 15, ty = tid >> 4;
  const int colbase = blockIdx.x * 64, rowbase = blockIdx.y * 64;

  float acc[4][4] = {};

  const int sr = tid >> 2, sc = (tid & 3) * 4;
  const int bk = tid >> 4, bn = (tid & 15) * 4;

  for (int kt = 0; kt < 64; ++kt) {
    const int k0 = kt * 16;
    const float4 av = *(const float4*)(x + (size_t)(rowbase + sr) * 1024 + k0 + sc);
    const float4 bv =
        *(const float4*)(w + (size_t)(k0 + bk) * 3072 + 2048 + colbase + bn);
    __syncthreads();
    As[sc + 0][sr] = av.x;
    As[sc + 1][sr] = av.y;
    As[sc + 2][sr] = av.z;
    As[sc + 3][sr] = av.w;
    Bs[bk][bn + 0] = bv.x;
    Bs[bk][bn + 1] = bv.y;
    Bs[bk][bn + 2] = bv.z;
    Bs[bk][bn + 3] = bv.w;
    __syncthreads();
#pragma unroll
    for (int k = 0; k < 16; ++k) {
      float a[4], b[4];
#pragma unroll
      for (int i = 0; i < 4; ++i) a[i] = As[k][ty + 16 * i];
#pragma unroll
      for (int j = 0; j < 4; ++j) b[j] = Bs[k][tx + 16 * j];
#pragma unroll
      for (int i = 0; i < 4; ++i)
#pragma unroll
        for (int j = 0; j < 4; ++j) acc[i][j] = fmaf(a[i], b[j], acc[i][j]);
    }
  }

#pragma unroll
  for (int j = 0; j < 4; ++j) {
    const int col = colbase + tx + 16 * j;
    const float bias = bqkv[2048 + col];
    const int h = col >> 6, d = col & 63;
#pragma unroll
    for (int i = 0; i < 4; ++i) {
      const int row = rowbase + ty + 16 * i;
      const int b = row >> 11, n = row & 2047;
      Vf[((size_t)((b * HH + h) * HD + d)) * NN + n] = acc[i][j] + bias;
    }
  }
}

// ---------------------------------------------------------------------------
// Selection + softmax for one q-row (verified semantics, verbatim since R4).
// S = 2048 fp64 scores in LDS. Writes P (f32) into row-pair layout:
//   Pt[((i*4 + row/2)*64 + lane)*2 + (row&1)] for key = lane + 64*i.
// ---------------------------------------------------------------------------
__device__ __forceinline__ void do_select(const double* __restrict__ S,
                                          float* __restrict__ Pt,
                                          float* __restrict__ Zout, int lane,
                                          int row) {
  double sv[32];
#pragma unroll
  for (int i = 0; i < 32; ++i) sv[i] = S[lane + 64 * i];

  // row max (fp64)
  double mxd = sv[0];
#pragma unroll
  for (int i = 1; i < 32; ++i) mxd = fmax(mxd, sv[i]);
#pragma unroll
  for (int m = 1; m < 64; m <<= 1) mxd = fmax(mxd, __shfl_xor(mxd, m, 64));

  // monotone u32 keys from fp32 casts
  unsigned ka[32];
#pragma unroll
  for (int i = 0; i < 32; ++i) {
    const int ib = __float_as_int((float)sv[i]);
    ka[i] = (unsigned)ib ^ ((ib < 0) ? 0xFFFFFFFFu : 0x80000000u);
  }

  // binary search: largest T32 with count(ka >= T32) >= 204
  unsigned T32 = 0;
#pragma unroll 1
  for (int bit = 31; bit >= 0; --bit) {
    const unsigned cand = T32 | (1u << bit);
    int c = 0;
#pragma unroll
    for (int i = 0; i < 32; ++i) c += (ka[i] >= cand) ? 1 : 0;
#pragma unroll
    for (int m = 1; m < 64; m <<= 1) c += __shfl_xor(c, m, 64);
    if (c >= KSP) T32 = cand;
  }

  // exact-tie accounting
  int cpk = 0;
#pragma unroll
  for (int i = 0; i < 32; ++i)
    cpk += (ka[i] > T32) ? (1 << 12) : ((ka[i] == T32) ? 1 : 0);
#pragma unroll
  for (int m = 1; m < 64; m <<= 1) cpk += __shfl_xor(cpk, m, 64);
  const int cgt = cpk >> 12, ceq = cpk & 0xFFF;

  unsigned selmask = 0;
  if (cgt + ceq == KSP) {
#pragma unroll
    for (int i = 0; i < 32; ++i) selmask |= (ka[i] >= T32) ? (1u << i) : 0u;
  } else {  // rare: resolve with exact fp64 keys
    unsigned long long T = 0ull;
#pragma unroll 1
    for (int bit = 63; bit >= 0; --bit) {
      const unsigned long long cand = T | (1ull << bit);
      int c = 0;
#pragma unroll
      for (int i = 0; i < 32; ++i)
        c += (ka[i] == T32 && mono64(sv[i]) >= cand) ? 1 : 0;
#pragma unroll
      for (int m = 1; m < 64; m <<= 1) c += __shfl_xor(c, m, 64);
      if (cgt + c >= KSP) T = cand;
    }
#pragma unroll
    for (int i = 0; i < 32; ++i)
      selmask |= ((ka[i] > T32) || (ka[i] == T32 && mono64(sv[i]) >= T))
                     ? (1u << i)
                     : 0u;
  }

  // softmax numerators (f32, row-pair layout) + Z
  const int p0 = row >> 1, h0 = row & 1;
  float z = 0.f;
#pragma unroll
  for (int i = 0; i < 32; ++i) {
    const float p = ((selmask >> i) & 1u) ? __expf((float)(sv[i] - mxd)) : 0.0f;
    Pt[((i * 4 + p0) * 64 + lane) * 2 + h0] = p;
    z += p;
  }
#pragma unroll
  for (int m = 1; m < 64; m <<= 1) z += __shfl_xor(z, m, 64);
  if (lane == 0) *Zout = z;
}

// ---------------------------------------------------------------------------
// Kernel 2: fused sparse attention — barrier-free QK streaming from L2.
// Block 512 thr = 8 waves; 8 q-rows. Wave w owns keys [256w, 256w+256).
// ---------------------------------------------------------------------------
__global__ __launch_bounds__(512) void attn_exact(
    const double* __restrict__ Qd, const double* __restrict__ Kd,
    const float* __restrict__ Vf, float* __restrict__ attnv) {
  __shared__ double TS[8192];     // 64KB: score-transpose scratch (4 rows)
  __shared__ float Pt[16384];     // 64KB: P, row-pair layout [32][4][64][2]
  __shared__ double Qrow[8][64];  // 4KB
  __shared__ float Zrow[8];

  const int tid = threadIdx.x;
  const int lane = tid & 63;
  const int w = tid >> 6;

  // XCD-chunked swizzle (bijective, 8192 % 8 == 0)
  const int bid = (int)(blockIdx.x & 7) * 1024 + ((int)blockIdx.x >> 3);
  const int bh = bid >> 8;
  const int n0 = (bid & 255) * 8;

  Qrow[w][lane] = Qd[((size_t)bh * HD + lane) * NN + n0 + w];
  __syncthreads();

  // ---- QK^T: stream K from L2, no barriers. acc[r][j], key=256w+lane+64j,
  //      fp64 FMA in d-ascending order (bit-identical to R3..R6). ----
  double acc[8][4];
#pragma unroll
  for (int r = 0; r < 8; ++r)
#pragma unroll
    for (int j = 0; j < 4; ++j) acc[r][j] = 0.0;

  {
    const double* kp = Kd + (size_t)bh * HD * NN + w * 256 + lane;
#pragma unroll 4
    for (int d = 0; d < 64; ++d) {
      const double* kr = kp + (size_t)d * NN;
      double kv[4];
#pragma unroll
      for (int j = 0; j < 4; ++j) kv[j] = kr[64 * j];
      double q[8];
#pragma unroll
      for (int r = 0; r < 8; ++r) q[r] = Qrow[r][d];
#pragma unroll
      for (int r = 0; r < 8; ++r)
#pragma unroll
        for (int j = 0; j < 4; ++j) acc[r][j] = fma(q[r], kv[j], acc[r][j]);
    }
  }

  // ---- transpose halves (LITERAL h -> acc stays in registers) ----
#define TRANS_HALF(hh)                                                       \
  {                                                                          \
    _Pragma("unroll") for (int lr = 0; lr < 4; ++lr)                         \
        _Pragma("unroll") for (int j = 0; j < 4; ++j)                        \
            TS[lr * 2048 + w * 256 + lane + 64 * j] = acc[4 * (hh) + lr][j]; \
    __syncthreads();                                                         \
    if ((w >> 2) == (hh))                                                    \
      do_select(&TS[(w & 3) * 2048], Pt, &Zrow[w], lane, w);                 \
    __syncthreads();                                                         \
  }

  TRANS_HALF(0)
  TRANS_HALF(1)

  // ---- PV: wave w owns d in [w*8, w*8+8); lane owns keys lane+64i ----
  const int b2 = bh >> 4, h2 = bh & 15;
#pragma unroll 1
  for (int dd = 0; dd < 8; ++dd) {
    const int d = w * 8 + dd;
    const float* vr = Vf + ((size_t)bh * HD + d) * NN + lane;
    float vv[32];
#pragma unroll
    for (int i = 0; i < 32; ++i) vv[i] = vr[i * 64];
    float s[8];
#pragma unroll
    for (int r = 0; r < 8; ++r) s[r] = 0.f;
#pragma unroll
    for (int i = 0; i < 32; ++i) {
      const float v = vv[i];
      const float2 p01 = *(const float2*)&Pt[((i * 4 + 0) * 64 + lane) * 2];
      const float2 p23 = *(const float2*)&Pt[((i * 4 + 1) * 64 + lane) * 2];
      const float2 p45 = *(const float2*)&Pt[((i * 4 + 2) * 64 + lane) * 2];
      const float2 p67 = *(const float2*)&Pt[((i * 4 + 3) * 64 + lane) * 2];
      s[0] = fmaf(p01.x, v, s[0]);
      s[1] = fmaf(p01.y, v, s[1]);
      s[2] = fmaf(p23.x, v, s[2]);
      s[3] = fmaf(p23.y, v, s[3]);
      s[4] = fmaf(p45.x, v, s[4]);
      s[5] = fmaf(p45.y, v, s[5]);
      s[6] = fmaf(p67.x, v, s[6]);
      s[7] = fmaf(p67.y, v, s[7]);
    }
#pragma unroll
    for (int r = 0; r < 8; ++r) {
#pragma unroll
      for (int m = 1; m < 64; m <<= 1) s[r] += __shfl_xor(s[r], m, 64);
      if (lane == 0)
        attnv[((size_t)(b2 * NN + n0 + r)) * CC + h2 * HD + d] = s[r] / Zrow[r];
    }
  }
}

// ---------------------------------------------------------------------------
// Kernel 3: out = attnv @ w_out + b_out, fp32, 64x64 tile, 4x4 micro.
// ---------------------------------------------------------------------------
__global__ __launch_bounds__(256) void out_gemm_f32(
    const float* __restrict__ A, const float* __restrict__ W,
    const float* __restrict__ bout, float* __restrict__ out) {
  __shared__ float As[16][64];
  __shared__ float Bs[16][64];
  const int tid = threadIdx.x;
  const int tx = tid & 15, ty = tid >> 4;
  const int colbase = blockIdx.x * 64, rowbase = blockIdx.y * 64;

  float acc[4][4] = {};

  const int sr = tid >> 2, sc = (tid & 3) * 4;
  const int bk = tid >> 4, bn = (tid & 15) * 4;

  for (int kt = 0; kt < 64; ++kt) {
    const int k0 = kt * 16;
    const float4 av = *(const float4*)(A + (size_t)(rowbase + sr) * 1024 + k0 + sc);
    const float4 bv = *(const float4*)(W + (size_t)(k0 + bk) * 1024 + colbase + bn);
    __syncthreads();
    As[sc + 0][sr] = av.x;
    As[sc + 1][sr] = av.y;
    As[sc + 2][sr] = av.z;
    As[sc + 3][sr] = av.w;
    Bs[bk][bn + 0] = bv.x;
    Bs[bk][bn + 1] = bv.y;
    Bs[bk][bn + 2] = bv.z;
    Bs[bk][bn + 3] = bv.w;
    __syncthreads();
#pragma unroll
    for (int k = 0; k < 16; ++k) {
      float a[4], b[4];
#pragma unroll
      for (int i = 0; i < 4; ++i) a[i] = As[k][ty + 16 * i];
#pragma unroll
      for (int j = 0; j < 4; ++j) b[j] = Bs[k][tx + 16 * j];
#pragma unroll
      for (int i = 0; i < 4; ++i)
#pragma unroll
        for (int j = 0; j < 4; ++j) acc[i][j] = fmaf(a[i], b[j], acc[i][j]);
    }
  }

#pragma unroll
  for (int j = 0; j < 4; ++j) {
    const int col = colbase + tx + 16 * j;
    const float bias = bout[col];
#pragma unroll
    for (int i = 0; i < 4; ++i) {
      const int row = rowbase + ty + 16 * i;
      out[(size_t)row * CC + col] = acc[i][j] + bias;
    }
  }
}

// ---------------------------------------------------------------------------
extern "C" void kernel_launch(void* const* d_in, const int* in_sizes, int n_in,
                              void* d_out, int out_size, void* d_ws,
                              size_t ws_size, hipStream_t stream) {
  const float* x     = (const float*)d_in[0];
  const float* w_qkv = (const float*)d_in[1];
  const float* b_qkv = (const float*)d_in[2];
  const float* w_out = (const float*)d_in[3];
  const float* b_out = (const float*)d_in[4];
  float* out = (float*)d_out;

  char* ws = (char*)d_ws;
  const size_t SZ_QD = (size_t)BB * HH * HD * NN * 8;  // 33.55 MB
  const size_t SZ_VF = (size_t)BB * HH * HD * NN * 4;  // 16.78 MB
  const size_t SZ_AT = (size_t)4096 * 1024 * 4;        // 16.78 MB

  size_t off = 0;
  double* Qd    = (double*)(ws + off); off += SZ_QD;
  double* Kd    = (double*)(ws + off); off += SZ_QD;
  float*  Vf    = (float*)(ws + off);  off += SZ_VF;
  float*  attnv = (float*)(ws + off);  off += SZ_AT;

  {
    dim3 g(2048 / 64, 4096 / 64);
    qk_gemm_f64<<<g, 256, 0, stream>>>(x, w_qkv, b_qkv, Qd, Kd);
  }
  {
    dim3 g(1024 / 64, 4096 / 64);
    v_gemm_f32<<<g, 256, 0, stream>>>(x, w_qkv, b_qkv, Vf);
  }
  attn_exact<<<BB * HH * (NN / 8), 512, 0, stream>>>(Qd, Kd, Vf, attnv);
  {
    dim3 g(1024 / 64, 4096 / 64);
    out_gemm_f32<<<g, 256, 0, stream>>>(attnv, w_out, b_out, out);
  }
}

// Round 8
// 3176.256 us; speedup vs baseline: 2.0038x; 2.0038x over previous
//
#include <hip/hip_runtime.h>
#include <cstdint>

// ---------------------------------------------------------------------------
// SparseAttention — R8: R7 structure (barrier-free QK streaming from L2) with
// the register budget fixed: __launch_bounds__(512,2) -> 256 VGPR (R7's
// implicit 128-cap spilled the load pipeline -> 2GB scratch traffic + L2
// pollution; counters: WRITE 1.08GB, FETCH 1.5GB). Also: QrowT b128 Q reads,
// PV loop-swapped (P read once per key: 128 ds_read_b64/thread vs 1024).
// Selection semantics bit-identical to R3..R7 (absmax must stay 2.563e-3).
// ---------------------------------------------------------------------------

#define BB 2
#define NN 2048
#define CC 1024
#define HH 16
#define HD 64
#define KSP 204

__device__ __forceinline__ unsigned long long mono64(double s) {
  long long bb = __double_as_longlong(s);
  return (unsigned long long)bb ^
         ((bb < 0) ? 0xFFFFFFFFFFFFFFFFull : 0x8000000000000000ull);
}

// ---------------------------------------------------------------------------
// Kernel 1: Q,K projection in fp64. 64x64 tile, 4x4 micro. Cols [0,2048).
// ---------------------------------------------------------------------------
__global__ __launch_bounds__(256) void qk_gemm_f64(
    const float* __restrict__ x, const float* __restrict__ w,
    const float* __restrict__ bqkv, double* __restrict__ Qd,
    double* __restrict__ Kd) {
  __shared__ double As[16][64];  // [k][m]
  __shared__ double Bs[16][64];  // [k][n]
  const int tid = threadIdx.x;
  const int tx = tid & 15, ty = tid >> 4;
  const int colbase = blockIdx.x * 64, rowbase = blockIdx.y * 64;

  double acc[4][4] = {};

  const int sr = tid >> 2, sc = (tid & 3) * 4;
  const int bk = tid >> 4, bn = (tid & 15) * 4;

  for (int kt = 0; kt < 64; ++kt) {
    const int k0 = kt * 16;
    const float4 av = *(const float4*)(x + (size_t)(rowbase + sr) * 1024 + k0 + sc);
    const float4 bv = *(const float4*)(w + (size_t)(k0 + bk) * 3072 + colbase + bn);
    __syncthreads();
    As[sc + 0][sr] = (double)av.x;
    As[sc + 1][sr] = (double)av.y;
    As[sc + 2][sr] = (double)av.z;
    As[sc + 3][sr] = (double)av.w;
    Bs[bk][bn + 0] = (double)bv.x;
    Bs[bk][bn + 1] = (double)bv.y;
    Bs[bk][bn + 2] = (double)bv.z;
    Bs[bk][bn + 3] = (double)bv.w;
    __syncthreads();
#pragma unroll
    for (int k = 0; k < 16; ++k) {
      double a[4], b[4];
#pragma unroll
      for (int i = 0; i < 4; ++i) a[i] = As[k][ty + 16 * i];
#pragma unroll
      for (int j = 0; j < 4; ++j) b[j] = Bs[k][tx + 16 * j];
#pragma unroll
      for (int i = 0; i < 4; ++i)
#pragma unroll
        for (int j = 0; j < 4; ++j) acc[i][j] = fma(a[i], b[j], acc[i][j]);
    }
  }

  const int region = colbase >> 10;  // 0=Q 1=K (uniform per block)
#pragma unroll
  for (int j = 0; j < 4; ++j) {
    const int col = colbase + tx + 16 * j;
    const double bias = (double)bqkv[col];
    const int h = (col & 1023) >> 6, d = col & 63;
#pragma unroll
    for (int i = 0; i < 4; ++i) {
      const int row = rowbase + ty + 16 * i;
      const int b = row >> 11, n = row & 2047;
      const size_t o = ((size_t)((b * HH + h) * HD + d)) * NN + n;
      const double v = acc[i][j] + bias;
      if (region == 0)
        Qd[o] = v * 0.125;
      else
        Kd[o] = v;
    }
  }
}

// ---------------------------------------------------------------------------
// Kernel 1b: V projection in fp32. Cols [2048,3072) of w_qkv.
// ---------------------------------------------------------------------------
__global__ __launch_bounds__(256) void v_gemm_f32(
    const float* __restrict__ x, const float* __restrict__ w,
    const float* __restrict__ bqkv, float* __restrict__ Vf) {
  __shared__ float As[16][64];
  __shared__ float Bs[16][64];
  const int tid = threadIdx.x;
  const int tx = tid & 15, ty = tid >> 4;
  const int colbase = blockIdx.x * 64, rowbase = blockIdx.y * 64;

  float acc[4][4] = {};

  const int sr = tid >> 2, sc = (tid & 3) * 4;
  const int bk = tid >> 4, bn = (tid & 15) * 4;

  for (int kt = 0; kt < 64; ++kt) {
    const int k0 = kt * 16;
    const float4 av = *(const float4*)(x + (size_t)(rowbase + sr) * 1024 + k0 + sc);
    const float4 bv =
        *(const float4*)(w + (size_t)(k0 + bk) * 3072 + 2048 + colbase + bn);
    __syncthreads();
    As[sc + 0][sr] = av.x;
    As[sc + 1][sr] = av.y;
    As[sc + 2][sr] = av.z;
    As[sc + 3][sr] = av.w;
    Bs[bk][bn + 0] = bv.x;
    Bs[bk][bn + 1] = bv.y;
    Bs[bk][bn + 2] = bv.z;
    Bs[bk][bn + 3] = bv.w;
    __syncthreads();
#pragma unroll
    for (int k = 0; k < 16; ++k) {
      float a[4], b[4];
#pragma unroll
      for (int i = 0; i < 4; ++i) a[i] = As[k][ty + 16 * i];
#pragma unroll
      for (int j = 0; j < 4; ++j) b[j] = Bs[k][tx + 16 * j];
#pragma unroll
      for (int i = 0; i < 4; ++i)
#pragma unroll
        for (int j = 0; j < 4; ++j) acc[i][j] = fmaf(a[i], b[j], acc[i][j]);
    }
  }

#pragma unroll
  for (int j = 0; j < 4; ++j) {
    const int col = colbase + tx + 16 * j;
    const float bias = bqkv[2048 + col];
    const int h = col >> 6, d = col & 63;
#pragma unroll
    for (int i = 0; i < 4; ++i) {
      const int row = rowbase + ty + 16 * i;
      const int b = row >> 11, n = row & 2047;
      Vf[((size_t)((b * HH + h) * HD + d)) * NN + n] = acc[i][j] + bias;
    }
  }
}

// ---------------------------------------------------------------------------
// Selection + softmax for one q-row (verified semantics, verbatim since R4).
// S = 2048 fp64 scores in LDS. Writes P (f32) into row-pair layout:
//   Pt[((i*4 + row/2)*64 + lane)*2 + (row&1)] for key = lane + 64*i.
// ---------------------------------------------------------------------------
__device__ __forceinline__ void do_select(const double* __restrict__ S,
                                          float* __restrict__ Pt,
                                          float* __restrict__ Zout, int lane,
                                          int row) {
  double sv[32];
#pragma unroll
  for (int i = 0; i < 32; ++i) sv[i] = S[lane + 64 * i];

  // row max (fp64)
  double mxd = sv[0];
#pragma unroll
  for (int i = 1; i < 32; ++i) mxd = fmax(mxd, sv[i]);
#pragma unroll
  for (int m = 1; m < 64; m <<= 1) mxd = fmax(mxd, __shfl_xor(mxd, m, 64));

  // monotone u32 keys from fp32 casts
  unsigned ka[32];
#pragma unroll
  for (int i = 0; i < 32; ++i) {
    const int ib = __float_as_int((float)sv[i]);
    ka[i] = (unsigned)ib ^ ((ib < 0) ? 0xFFFFFFFFu : 0x80000000u);
  }

  // binary search: largest T32 with count(ka >= T32) >= 204
  unsigned T32 = 0;
#pragma unroll 1
  for (int bit = 31; bit >= 0; --bit) {
    const unsigned cand = T32 | (1u << bit);
    int c = 0;
#pragma unroll
    for (int i = 0; i < 32; ++i) c += (ka[i] >= cand) ? 1 : 0;
#pragma unroll
    for (int m = 1; m < 64; m <<= 1) c += __shfl_xor(c, m, 64);
    if (c >= KSP) T32 = cand;
  }

  // exact-tie accounting
  int cpk = 0;
#pragma unroll
  for (int i = 0; i < 32; ++i)
    cpk += (ka[i] > T32) ? (1 << 12) : ((ka[i] == T32) ? 1 : 0);
#pragma unroll
  for (int m = 1; m < 64; m <<= 1) cpk += __shfl_xor(cpk, m, 64);
  const int cgt = cpk >> 12, ceq = cpk & 0xFFF;

  unsigned selmask = 0;
  if (cgt + ceq == KSP) {
#pragma unroll
    for (int i = 0; i < 32; ++i) selmask |= (ka[i] >= T32) ? (1u << i) : 0u;
  } else {  // rare: resolve with exact fp64 keys
    unsigned long long T = 0ull;
#pragma unroll 1
    for (int bit = 63; bit >= 0; --bit) {
      const unsigned long long cand = T | (1ull << bit);
      int c = 0;
#pragma unroll
      for (int i = 0; i < 32; ++i)
        c += (ka[i] == T32 && mono64(sv[i]) >= cand) ? 1 : 0;
#pragma unroll
      for (int m = 1; m < 64; m <<= 1) c += __shfl_xor(c, m, 64);
      if (cgt + c >= KSP) T = cand;
    }
#pragma unroll
    for (int i = 0; i < 32; ++i)
      selmask |= ((ka[i] > T32) || (ka[i] == T32 && mono64(sv[i]) >= T))
                     ? (1u << i)
                     : 0u;
  }

  // softmax numerators (f32, row-pair layout) + Z
  const int p0 = row >> 1, h0 = row & 1;
  float z = 0.f;
#pragma unroll
  for (int i = 0; i < 32; ++i) {
    const float p = ((selmask >> i) & 1u) ? __expf((float)(sv[i] - mxd)) : 0.0f;
    Pt[((i * 4 + p0) * 64 + lane) * 2 + h0] = p;
    z += p;
  }
#pragma unroll
  for (int m = 1; m < 64; m <<= 1) z += __shfl_xor(z, m, 64);
  if (lane == 0) *Zout = z;
}

// ---------------------------------------------------------------------------
// Kernel 2: fused sparse attention — barrier-free QK streaming from L2.
// Block 512 thr = 8 waves; 8 q-rows. Wave w owns keys [256w, 256w+256).
// __launch_bounds__(512,2): 2 waves/SIMD -> 256 VGPR budget (no spill).
// ---------------------------------------------------------------------------
__global__ __launch_bounds__(512, 2) void attn_exact(
    const double* __restrict__ Qd, const double* __restrict__ Kd,
    const float* __restrict__ Vf, float* __restrict__ attnv) {
  __shared__ double TS[8192];                 // 64KB: score-transpose scratch
  __shared__ float Pt[16384];                 // 64KB: P row-pair layout
  __shared__ __align__(16) double QrowT[64][8];  // 4KB: [d][row]
  __shared__ float Zrow[8];

  const int tid = threadIdx.x;
  const int lane = tid & 63;
  const int w = tid >> 6;

  // XCD-chunked swizzle (bijective, 8192 % 8 == 0)
  const int bid = (int)(blockIdx.x & 7) * 1024 + ((int)blockIdx.x >> 3);
  const int bh = bid >> 8;
  const int n0 = (bid & 255) * 8;

  QrowT[lane][w] = Qd[((size_t)bh * HD + lane) * NN + n0 + w];
  __syncthreads();

  // ---- QK^T: stream K from L2, no barriers. acc[r][j], key=256w+lane+64j,
  //      fp64 FMA in d-ascending order (bit-identical to R3..R7). ----
  double acc[8][4];
#pragma unroll
  for (int r = 0; r < 8; ++r)
#pragma unroll
    for (int j = 0; j < 4; ++j) acc[r][j] = 0.0;

  {
    const double* kp = Kd + (size_t)bh * HD * NN + w * 256 + lane;
#pragma unroll 4
    for (int d = 0; d < 64; ++d) {
      const double* kr = kp + (size_t)d * NN;
      double kv[4];
#pragma unroll
      for (int j = 0; j < 4; ++j) kv[j] = kr[64 * j];
      double q[8];
#pragma unroll
      for (int r = 0; r < 8; ++r) q[r] = QrowT[d][r];
#pragma unroll
      for (int r = 0; r < 8; ++r)
#pragma unroll
        for (int j = 0; j < 4; ++j) acc[r][j] = fma(q[r], kv[j], acc[r][j]);
    }
  }

  // ---- transpose halves (LITERAL h -> acc stays in registers) ----
#define TRANS_HALF(hh)                                                       \
  {                                                                          \
    _Pragma("unroll") for (int lr = 0; lr < 4; ++lr)                         \
        _Pragma("unroll") for (int j = 0; j < 4; ++j)                        \
            TS[lr * 2048 + w * 256 + lane + 64 * j] = acc[4 * (hh) + lr][j]; \
    __syncthreads();                                                         \
    if ((w >> 2) == (hh))                                                    \
      do_select(&TS[(w & 3) * 2048], Pt, &Zrow[w], lane, w);                 \
    __syncthreads();                                                         \
  }

  TRANS_HALF(0)
  TRANS_HALF(1)

  // ---- PV: wave w owns d in [w*8, w*8+8); keys outer, P read once ----
  const int b2 = bh >> 4, h2 = bh & 15;
  {
    float s[8][8];  // [dd][r]
#pragma unroll
    for (int dd = 0; dd < 8; ++dd)
#pragma unroll
      for (int r = 0; r < 8; ++r) s[dd][r] = 0.f;

    const float* vb = Vf + ((size_t)bh * HD + w * 8) * NN + lane;
#pragma unroll 2
    for (int i = 0; i < 32; ++i) {
      const float2 p01 = *(const float2*)&Pt[((i * 4 + 0) * 64 + lane) * 2];
      const float2 p23 = *(const float2*)&Pt[((i * 4 + 1) * 64 + lane) * 2];
      const float2 p45 = *(const float2*)&Pt[((i * 4 + 2) * 64 + lane) * 2];
      const float2 p67 = *(const float2*)&Pt[((i * 4 + 3) * 64 + lane) * 2];
      float vvv[8];
#pragma unroll
      for (int dd = 0; dd < 8; ++dd) vvv[dd] = vb[(size_t)dd * NN + 64 * i];
#pragma unroll
      for (int dd = 0; dd < 8; ++dd) {
        const float v = vvv[dd];
        s[dd][0] = fmaf(p01.x, v, s[dd][0]);
        s[dd][1] = fmaf(p01.y, v, s[dd][1]);
        s[dd][2] = fmaf(p23.x, v, s[dd][2]);
        s[dd][3] = fmaf(p23.y, v, s[dd][3]);
        s[dd][4] = fmaf(p45.x, v, s[dd][4]);
        s[dd][5] = fmaf(p45.y, v, s[dd][5]);
        s[dd][6] = fmaf(p67.x, v, s[dd][6]);
        s[dd][7] = fmaf(p67.y, v, s[dd][7]);
      }
    }
#pragma unroll
    for (int dd = 0; dd < 8; ++dd) {
#pragma unroll
      for (int r = 0; r < 8; ++r) {
        float v = s[dd][r];
#pragma unroll
        for (int m = 1; m < 64; m <<= 1) v += __shfl_xor(v, m, 64);
        if (lane == 0)
          attnv[((size_t)(b2 * NN + n0 + r)) * CC + h2 * HD + w * 8 + dd] =
              v / Zrow[r];
      }
    }
  }
}

// ---------------------------------------------------------------------------
// Kernel 3: out = attnv @ w_out + b_out, fp32, 64x64 tile, 4x4 micro.
// ---------------------------------------------------------------------------
__global__ __launch_bounds__(256) void out_gemm_f32(
    const float* __restrict__ A, const float* __restrict__ W,
    const float* __restrict__ bout, float* __restrict__ out) {
  __shared__ float As[16][64];
  __shared__ float Bs[16][64];
  const int tid = threadIdx.x;
  const int tx = tid & 15, ty = tid >> 4;
  const int colbase = blockIdx.x * 64, rowbase = blockIdx.y * 64;

  float acc[4][4] = {};

  const int sr = tid >> 2, sc = (tid & 3) * 4;
  const int bk = tid >> 4, bn = (tid & 15) * 4;

  for (int kt = 0; kt < 64; ++kt) {
    const int k0 = kt * 16;
    const float4 av = *(const float4*)(A + (size_t)(rowbase + sr) * 1024 + k0 + sc);
    const float4 bv = *(const float4*)(W + (size_t)(k0 + bk) * 1024 + colbase + bn);
    __syncthreads();
    As[sc + 0][sr] = av.x;
    As[sc + 1][sr] = av.y;
    As[sc + 2][sr] = av.z;
    As[sc + 3][sr] = av.w;
    Bs[bk][bn + 0] = bv.x;
    Bs[bk][bn + 1] = bv.y;
    Bs[bk][bn + 2] = bv.z;
    Bs[bk][bn + 3] = bv.w;
    __syncthreads();
#pragma unroll
    for (int k = 0; k < 16; ++k) {
      float a[4], b[4];
#pragma unroll
      for (int i = 0; i < 4; ++i) a[i] = As[k][ty + 16 * i];
#pragma unroll
      for (int j = 0; j < 4; ++j) b[j] = Bs[k][tx + 16 * j];
#pragma unroll
      for (int i = 0; i < 4; ++i)
#pragma unroll
        for (int j = 0; j < 4; ++j) acc[i][j] = fmaf(a[i], b[j], acc[i][j]);
    }
  }

#pragma unroll
  for (int j = 0; j < 4; ++j) {
    const int col = colbase + tx + 16 * j;
    const float bias = bout[col];
#pragma unroll
    for (int i = 0; i < 4; ++i) {
      const int row = rowbase + ty + 16 * i;
      out[(size_t)row * CC + col] = acc[i][j] + bias;
    }
  }
}

// ---------------------------------------------------------------------------
extern "C" void kernel_launch(void* const* d_in, const int* in_sizes, int n_in,
                              void* d_out, int out_size, void* d_ws,
                              size_t ws_size, hipStream_t stream) {
  const float* x     = (const float*)d_in[0];
  const float* w_qkv = (const float*)d_in[1];
  const float* b_qkv = (const float*)d_in[2];
  const float* w_out = (const float*)d_in[3];
  const float* b_out = (const float*)d_in[4];
  float* out = (float*)d_out;

  char* ws = (char*)d_ws;
  const size_t SZ_QD = (size_t)BB * HH * HD * NN * 8;  // 33.55 MB
  const size_t SZ_VF = (size_t)BB * HH * HD * NN * 4;  // 16.78 MB
  const size_t SZ_AT = (size_t)4096 * 1024 * 4;        // 16.78 MB

  size_t off = 0;
  double* Qd    = (double*)(ws + off); off += SZ_QD;
  double* Kd    = (double*)(ws + off); off += SZ_QD;
  float*  Vf    = (float*)(ws + off);  off += SZ_VF;
  float*  attnv = (float*)(ws + off);  off += SZ_AT;

  {
    dim3 g(2048 / 64, 4096 / 64);
    qk_gemm_f64<<<g, 256, 0, stream>>>(x, w_qkv, b_qkv, Qd, Kd);
  }
  {
    dim3 g(1024 / 64, 4096 / 64);
    v_gemm_f32<<<g, 256, 0, stream>>>(x, w_qkv, b_qkv, Vf);
  }
  attn_exact<<<BB * HH * (NN / 8), 512, 0, stream>>>(Qd, Kd, Vf, attnv);
  {
    dim3 g(1024 / 64, 4096 / 64);
    out_gemm_f32<<<g, 256, 0, stream>>>(attnv, w_out, b_out, out);
  }
}

// Round 9
// 2984.089 us; speedup vs baseline: 2.1328x; 1.0644x over previous
//
#include <hip/hip_runtime.h>
#include <cstdint>

// ---------------------------------------------------------------------------
// SparseAttention — R9: occupancy round. R8 counters: 1 block/CU (LDS 135KB),
// VALUBusy 37%, latency-bound. This round: LDS 135KB -> ~68KB (2 blocks/CU):
//   - TS transpose scratch 64KB -> 32KB (4 phases x 2 rows)
//   - P f32 64KB -> f16 key-major Pp[key][8] 32KB (b128 read/key in PV;
//     f16 P verified safe in R4/R6 — identical absmax)
//   - do_select re-reads scores from LDS (drops sv[32] = 64 VGPRs)
//   - PV in two dd-halves (s[4][8]); launch_bounds(512,4) pins 128 VGPR
//   - double2 K loads, float4 V loads (PV key remap — smooth path only)
// Selection op-for-op identical to R3..R8 (d-ascending fp64 FMA, fp32-cast
// u32 keys, exact-tie fp64 fallback) => same selected set.
// ---------------------------------------------------------------------------

#define BB 2
#define NN 2048
#define CC 1024
#define HH 16
#define HD 64
#define KSP 204

typedef _Float16 f16x8v __attribute__((ext_vector_type(8)));

__device__ __forceinline__ unsigned long long mono64(double s) {
  long long bb = __double_as_longlong(s);
  return (unsigned long long)bb ^
         ((bb < 0) ? 0xFFFFFFFFFFFFFFFFull : 0x8000000000000000ull);
}

// ---------------------------------------------------------------------------
// Kernel 1: Q,K projection in fp64. 64x64 tile, 4x4 micro. Cols [0,2048).
// ---------------------------------------------------------------------------
__global__ __launch_bounds__(256) void qk_gemm_f64(
    const float* __restrict__ x, const float* __restrict__ w,
    const float* __restrict__ bqkv, double* __restrict__ Qd,
    double* __restrict__ Kd) {
  __shared__ double As[16][64];  // [k][m]
  __shared__ double Bs[16][64];  // [k][n]
  const int tid = threadIdx.x;
  const int tx = tid & 15, ty = tid >> 4;
  const int colbase = blockIdx.x * 64, rowbase = blockIdx.y * 64;

  double acc[4][4] = {};

  const int sr = tid >> 2, sc = (tid & 3) * 4;
  const int bk = tid >> 4, bn = (tid & 15) * 4;

  for (int kt = 0; kt < 64; ++kt) {
    const int k0 = kt * 16;
    const float4 av = *(const float4*)(x + (size_t)(rowbase + sr) * 1024 + k0 + sc);
    const float4 bv = *(const float4*)(w + (size_t)(k0 + bk) * 3072 + colbase + bn);
    __syncthreads();
    As[sc + 0][sr] = (double)av.x;
    As[sc + 1][sr] = (double)av.y;
    As[sc + 2][sr] = (double)av.z;
    As[sc + 3][sr] = (double)av.w;
    Bs[bk][bn + 0] = (double)bv.x;
    Bs[bk][bn + 1] = (double)bv.y;
    Bs[bk][bn + 2] = (double)bv.z;
    Bs[bk][bn + 3] = (double)bv.w;
    __syncthreads();
#pragma unroll
    for (int k = 0; k < 16; ++k) {
      double a[4], b[4];
#pragma unroll
      for (int i = 0; i < 4; ++i) a[i] = As[k][ty + 16 * i];
#pragma unroll
      for (int j = 0; j < 4; ++j) b[j] = Bs[k][tx + 16 * j];
#pragma unroll
      for (int i = 0; i < 4; ++i)
#pragma unroll
        for (int j = 0; j < 4; ++j) acc[i][j] = fma(a[i], b[j], acc[i][j]);
    }
  }

  const int region = colbase >> 10;  // 0=Q 1=K (uniform per block)
#pragma unroll
  for (int j = 0; j < 4; ++j) {
    const int col = colbase + tx + 16 * j;
    const double bias = (double)bqkv[col];
    const int h = (col & 1023) >> 6, d = col & 63;
#pragma unroll
    for (int i = 0; i < 4; ++i) {
      const int row = rowbase + ty + 16 * i;
      const int b = row >> 11, n = row & 2047;
      const size_t o = ((size_t)((b * HH + h) * HD + d)) * NN + n;
      const double v = acc[i][j] + bias;
      if (region == 0)
        Qd[o] = v * 0.125;
      else
        Kd[o] = v;
    }
  }
}

// ---------------------------------------------------------------------------
// Kernel 1b: V projection in fp32. Cols [2048,3072) of w_qkv.
// ---------------------------------------------------------------------------
__global__ __launch_bounds__(256) void v_gemm_f32(
    const float* __restrict__ x, const float* __restrict__ w,
    const float* __restrict__ bqkv, float* __restrict__ Vf) {
  __shared__ float As[16][64];
  __shared__ float Bs[16][64];
  const int tid = threadIdx.x;
  const int tx = tid & 15, ty = tid >> 4;
  const int colbase = blockIdx.x * 64, rowbase = blockIdx.y * 64;

  float acc[4][4] = {};

  const int sr = tid >> 2, sc = (tid & 3) * 4;
  const int bk = tid >> 4, bn = (tid & 15) * 4;

  for (int kt = 0; kt < 64; ++kt) {
    const int k0 = kt * 16;
    const float4 av = *(const float4*)(x + (size_t)(rowbase + sr) * 1024 + k0 + sc);
    const float4 bv =
        *(const float4*)(w + (size_t)(k0 + bk) * 3072 + 2048 + colbase + bn);
    __syncthreads();
    As[sc + 0][sr] = av.x;
    As[sc + 1][sr] = av.y;
    As[sc + 2][sr] = av.z;
    As[sc + 3][sr] = av.w;
    Bs[bk][bn + 0] = bv.x;
    Bs[bk][bn + 1] = bv.y;
    Bs[bk][bn + 2] = bv.z;
    Bs[bk][bn + 3] = bv.w;
    __syncthreads();
#pragma unroll
    for (int k = 0; k < 16; ++k) {
      float a[4], b[4];
#pragma unroll
      for (int i = 0; i < 4; ++i) a[i] = As[k][ty + 16 * i];
#pragma unroll
      for (int j = 0; j < 4; ++j) b[j] = Bs[k][tx + 16 * j];
#pragma unroll
      for (int i = 0; i < 4; ++i)
#pragma unroll
        for (int j = 0; j < 4; ++j) acc[i][j] = fmaf(a[i], b[j], acc[i][j]);
    }
  }

#pragma unroll
  for (int j = 0; j < 4; ++j) {
    const int col = colbase + tx + 16 * j;
    const float bias = bqkv[2048 + col];
    const int h = col >> 6, d = col & 63;
#pragma unroll
    for (int i = 0; i < 4; ++i) {
      const int row = rowbase + ty + 16 * i;
      const int b = row >> 11, n = row & 2047;
      Vf[((size_t)((b * HH + h) * HD + d)) * NN + n] = acc[i][j] + bias;
    }
  }
}

// ---------------------------------------------------------------------------
// Selection + softmax for one q-row (verified semantics since R4).
// S = 2048 fp64 scores in LDS (re-read each pass — no sv[32] register array).
// Writes P (f16) key-major: Pp[key*8 + row]; Z to *Zout.
// ---------------------------------------------------------------------------
__device__ __forceinline__ void do_select(const double* __restrict__ S,
                                          _Float16* __restrict__ Pp,
                                          float* __restrict__ Zout, int lane,
                                          int row) {
  // row max (fp64)
  double mxd = -1.0e300;
#pragma unroll
  for (int i = 0; i < 32; ++i) mxd = fmax(mxd, S[lane + 64 * i]);
#pragma unroll
  for (int m = 1; m < 64; m <<= 1) mxd = fmax(mxd, __shfl_xor(mxd, m, 64));

  // monotone u32 keys from fp32 casts
  unsigned ka[32];
#pragma unroll
  for (int i = 0; i < 32; ++i) {
    const int ib = __float_as_int((float)S[lane + 64 * i]);
    ka[i] = (unsigned)ib ^ ((ib < 0) ? 0xFFFFFFFFu : 0x80000000u);
  }

  // binary search: largest T32 with count(ka >= T32) >= 204
  unsigned T32 = 0;
#pragma unroll 1
  for (int bit = 31; bit >= 0; --bit) {
    const unsigned cand = T32 | (1u << bit);
    int c = 0;
#pragma unroll
    for (int i = 0; i < 32; ++i) c += (ka[i] >= cand) ? 1 : 0;
#pragma unroll
    for (int m = 1; m < 64; m <<= 1) c += __shfl_xor(c, m, 64);
    if (c >= KSP) T32 = cand;
  }

  // exact-tie accounting
  int cpk = 0;
#pragma unroll
  for (int i = 0; i < 32; ++i)
    cpk += (ka[i] > T32) ? (1 << 12) : ((ka[i] == T32) ? 1 : 0);
#pragma unroll
  for (int m = 1; m < 64; m <<= 1) cpk += __shfl_xor(cpk, m, 64);
  const int cgt = cpk >> 12, ceq = cpk & 0xFFF;

  unsigned selmask = 0;
  if (cgt + ceq == KSP) {
#pragma unroll
    for (int i = 0; i < 32; ++i) selmask |= (ka[i] >= T32) ? (1u << i) : 0u;
  } else {  // rare: resolve with exact fp64 keys (re-read from LDS)
    unsigned long long T = 0ull;
#pragma unroll 1
    for (int bit = 63; bit >= 0; --bit) {
      const unsigned long long cand = T | (1ull << bit);
      int c = 0;
#pragma unroll
      for (int i = 0; i < 32; ++i)
        c += (ka[i] == T32 && mono64(S[lane + 64 * i]) >= cand) ? 1 : 0;
#pragma unroll
      for (int m = 1; m < 64; m <<= 1) c += __shfl_xor(c, m, 64);
      if (cgt + c >= KSP) T = cand;
    }
#pragma unroll
    for (int i = 0; i < 32; ++i)
      selmask |= ((ka[i] > T32) ||
                  (ka[i] == T32 && mono64(S[lane + 64 * i]) >= T))
                     ? (1u << i)
                     : 0u;
  }

  // softmax numerators (f16, key-major) + Z
  float z = 0.f;
#pragma unroll
  for (int i = 0; i < 32; ++i) {
    const float p = ((selmask >> i) & 1u)
                        ? __expf((float)(S[lane + 64 * i] - mxd))
                        : 0.0f;
    Pp[(lane + 64 * i) * 8 + row] = (_Float16)p;
    z += p;
  }
#pragma unroll
  for (int m = 1; m < 64; m <<= 1) z += __shfl_xor(z, m, 64);
  if (lane == 0) *Zout = z;
}

// ---------------------------------------------------------------------------
// Kernel 2: fused sparse attention. 8 waves, 8 q-rows, ~68KB LDS (2 blk/CU).
// QK: barrier-free L2 streaming, double2 loads, key = 256w + 2*lane + 128*j.
// 4 transpose phases (2 rows each, 32KB TS) -> select -> PV (f16 P b128).
// ---------------------------------------------------------------------------
__global__ __launch_bounds__(512, 4) void attn_exact(
    const double* __restrict__ Qd, const double* __restrict__ Kd,
    const float* __restrict__ Vf, float* __restrict__ attnv) {
  __shared__ double TS[4096];                    // 32KB: 2 score rows
  __shared__ _Float16 Pp[2048 * 8];              // 32KB: P key-major
  __shared__ __align__(16) double QrowT[64][8];  // 4KB: [d][row]
  __shared__ float Zrow[8];

  const int tid = threadIdx.x;
  const int lane = tid & 63;
  const int w = tid >> 6;

  // XCD-chunked swizzle (bijective, 8192 % 8 == 0)
  const int bid = (int)(blockIdx.x & 7) * 1024 + ((int)blockIdx.x >> 3);
  const int bh = bid >> 8;
  const int n0 = (bid & 255) * 8;

  QrowT[lane][w] = Qd[((size_t)bh * HD + lane) * NN + n0 + w];
  __syncthreads();

  // ---- QK^T: stream K from L2, no barriers.
  //      acc[r][j]: key = 256w + 2*lane + (j>>1)*128 + (j&1); d-ascending. ----
  double acc[8][4];
#pragma unroll
  for (int r = 0; r < 8; ++r)
#pragma unroll
    for (int j = 0; j < 4; ++j) acc[r][j] = 0.0;

  {
    const double* kp = Kd + (size_t)bh * HD * NN + w * 256 + 2 * lane;
#pragma unroll 4
    for (int d = 0; d < 64; ++d) {
      const double* kr = kp + (size_t)d * NN;
      const double2 kv0 = *(const double2*)(kr);
      const double2 kv1 = *(const double2*)(kr + 128);
      double q[8];
#pragma unroll
      for (int rp = 0; rp < 4; ++rp)
        *(double2*)&q[rp * 2] = *(const double2*)&QrowT[d][rp * 2];
#pragma unroll
      for (int r = 0; r < 8; ++r) {
        acc[r][0] = fma(q[r], kv0.x, acc[r][0]);
        acc[r][1] = fma(q[r], kv0.y, acc[r][1]);
        acc[r][2] = fma(q[r], kv1.x, acc[r][2]);
        acc[r][3] = fma(q[r], kv1.y, acc[r][3]);
      }
    }
  }

  // ---- 4 transpose phases (literal P -> acc stays in registers) ----
  // Phase P: rows 2P, 2P+1 -> TS[0..2047], TS[2048..4095]; selected by
  // waves 2P and 2P+1 respectively.
#define TRANS_PHASE(P)                                                        \
  {                                                                           \
    _Pragma("unroll") for (int rr = 0; rr < 2; ++rr) {                        \
      const int base = rr * 2048 + w * 256 + 2 * lane;                        \
      double2 w0, w1;                                                         \
      w0.x = acc[2 * (P) + rr][0];                                            \
      w0.y = acc[2 * (P) + rr][1];                                            \
      w1.x = acc[2 * (P) + rr][2];                                            \
      w1.y = acc[2 * (P) + rr][3];                                            \
      *(double2*)&TS[base] = w0;                                              \
      *(double2*)&TS[base + 128] = w1;                                        \
    }                                                                         \
    __syncthreads();                                                          \
    if (w == 2 * (P))                                                         \
      do_select(&TS[0], Pp, &Zrow[2 * (P)], lane, 2 * (P));                   \
    else if (w == 2 * (P) + 1)                                                \
      do_select(&TS[2048], Pp, &Zrow[2 * (P) + 1], lane, 2 * (P) + 1);        \
    __syncthreads();                                                          \
  }

  TRANS_PHASE(0)
  TRANS_PHASE(1)
  TRANS_PHASE(2)
  TRANS_PHASE(3)

  // ---- PV: wave w owns d in [w*8, w*8+8), two halves of 4; lane's keys
  //      are 4*lane + 256*ip (float4 V loads, b128 P loads). Smooth path. ----
  const int b2 = bh >> 4, h2 = bh & 15;
#define PV_HALF(H)                                                            \
  {                                                                           \
    float s[4][8];                                                            \
    _Pragma("unroll") for (int d4 = 0; d4 < 4; ++d4)                          \
        _Pragma("unroll") for (int r = 0; r < 8; ++r) s[d4][r] = 0.f;         \
    const float* vb = Vf + ((size_t)bh * HD + w * 8 + (H)*4) * NN;            \
    _Pragma("unroll 2") for (int ip = 0; ip < 8; ++ip) {                      \
      const int k0 = 4 * lane + 256 * ip;                                     \
      float pf[4][8];                                                         \
      _Pragma("unroll") for (int kk = 0; kk < 4; ++kk) {                      \
        const f16x8v pk = *(const f16x8v*)&Pp[(k0 + kk) * 8];                 \
        _Pragma("unroll") for (int r = 0; r < 8; ++r) pf[kk][r] =             \
            (float)pk[r];                                                     \
      }                                                                       \
      _Pragma("unroll") for (int d4 = 0; d4 < 4; ++d4) {                      \
        const float4 v4 = *(const float4*)(vb + (size_t)d4 * NN + k0);        \
        _Pragma("unroll") for (int r = 0; r < 8; ++r) {                       \
          s[d4][r] = fmaf(pf[0][r], v4.x, s[d4][r]);                          \
          s[d4][r] = fmaf(pf[1][r], v4.y, s[d4][r]);                          \
          s[d4][r] = fmaf(pf[2][r], v4.z, s[d4][r]);                          \
          s[d4][r] = fmaf(pf[3][r], v4.w, s[d4][r]);                          \
        }                                                                     \
      }                                                                       \
    }                                                                         \
    _Pragma("unroll") for (int d4 = 0; d4 < 4; ++d4)                          \
        _Pragma("unroll") for (int r = 0; r < 8; ++r) {                       \
      float v = s[d4][r];                                                     \
      _Pragma("unroll") for (int m = 1; m < 64; m <<= 1) v +=                 \
          __shfl_xor(v, m, 64);                                               \
      if (lane == 0)                                                          \
        attnv[((size_t)(b2 * NN + n0 + r)) * CC + h2 * HD + w * 8 + (H)*4 +   \
              d4] = v / Zrow[r];                                              \
    }                                                                         \
  }

  PV_HALF(0)
  PV_HALF(1)
}

// ---------------------------------------------------------------------------
// Kernel 3: out = attnv @ w_out + b_out, fp32, 64x64 tile, 4x4 micro.
// ---------------------------------------------------------------------------
__global__ __launch_bounds__(256) void out_gemm_f32(
    const float* __restrict__ A, const float* __restrict__ W,
    const float* __restrict__ bout, float* __restrict__ out) {
  __shared__ float As[16][64];
  __shared__ float Bs[16][64];
  const int tid = threadIdx.x;
  const int tx = tid & 15, ty = tid >> 4;
  const int colbase = blockIdx.x * 64, rowbase = blockIdx.y * 64;

  float acc[4][4] = {};

  const int sr = tid >> 2, sc = (tid & 3) * 4;
  const int bk = tid >> 4, bn = (tid & 15) * 4;

  for (int kt = 0; kt < 64; ++kt) {
    const int k0 = kt * 16;
    const float4 av = *(const float4*)(A + (size_t)(rowbase + sr) * 1024 + k0 + sc);
    const float4 bv = *(const float4*)(W + (size_t)(k0 + bk) * 1024 + colbase + bn);
    __syncthreads();
    As[sc + 0][sr] = av.x;
    As[sc + 1][sr] = av.y;
    As[sc + 2][sr] = av.z;
    As[sc + 3][sr] = av.w;
    Bs[bk][bn + 0] = bv.x;
    Bs[bk][bn + 1] = bv.y;
    Bs[bk][bn + 2] = bv.z;
    Bs[bk][bn + 3] = bv.w;
    __syncthreads();
#pragma unroll
    for (int k = 0; k < 16; ++k) {
      float a[4], b[4];
#pragma unroll
      for (int i = 0; i < 4; ++i) a[i] = As[k][ty + 16 * i];
#pragma unroll
      for (int j = 0; j < 4; ++j) b[j] = Bs[k][tx + 16 * j];
#pragma unroll
      for (int i = 0; i < 4; ++i)
#pragma unroll
        for (int j = 0; j < 4; ++j) acc[i][j] = fmaf(a[i], b[j], acc[i][j]);
    }
  }

#pragma unroll
  for (int j = 0; j < 4; ++j) {
    const int col = colbase + tx + 16 * j;
    const float bias = bout[col];
#pragma unroll
    for (int i = 0; i < 4; ++i) {
      const int row = rowbase + ty + 16 * i;
      out[(size_t)row * CC + col] = acc[i][j] + bias;
    }
  }
}

// ---------------------------------------------------------------------------
extern "C" void kernel_launch(void* const* d_in, const int* in_sizes, int n_in,
                              void* d_out, int out_size, void* d_ws,
                              size_t ws_size, hipStream_t stream) {
  const float* x     = (const float*)d_in[0];
  const float* w_qkv = (const float*)d_in[1];
  const float* b_qkv = (const float*)d_in[2];
  const float* w_out = (const float*)d_in[3];
  const float* b_out = (const float*)d_in[4];
  float* out = (float*)d_out;

  char* ws = (char*)d_ws;
  const size_t SZ_QD = (size_t)BB * HH * HD * NN * 8;  // 33.55 MB
  const size_t SZ_VF = (size_t)BB * HH * HD * NN * 4;  // 16.78 MB
  const size_t SZ_AT = (size_t)4096 * 1024 * 4;        // 16.78 MB

  size_t off = 0;
  double* Qd    = (double*)(ws + off); off += SZ_QD;
  double* Kd    = (double*)(ws + off); off += SZ_QD;
  float*  Vf    = (float*)(ws + off);  off += SZ_VF;
  float*  attnv = (float*)(ws + off);  off += SZ_AT;

  {
    dim3 g(2048 / 64, 4096 / 64);
    qk_gemm_f64<<<g, 256, 0, stream>>>(x, w_qkv, b_qkv, Qd, Kd);
  }
  {
    dim3 g(1024 / 64, 4096 / 64);
    v_gemm_f32<<<g, 256, 0, stream>>>(x, w_qkv, b_qkv, Vf);
  }
  attn_exact<<<BB * HH * (NN / 8), 512, 0, stream>>>(Qd, Kd, Vf, attnv);
  {
    dim3 g(1024 / 64, 4096 / 64);
    out_gemm_f32<<<g, 256, 0, stream>>>(attnv, w_out, b_out, out);
  }
}

// Round 10
// 2939.174 us; speedup vs baseline: 2.1654x; 1.0153x over previous
//
#include <hip/hip_runtime.h>
#include <cstdint>

// ---------------------------------------------------------------------------
// SparseAttention — R10: fit the register demand to the 128-VGPR/4-wave cap.
// attn: 1024 thr (16 waves), 8 q-rows; per-thread acc halves to acc[8][2]
// (32 VGPR) -> no spill at 16 waves/CU. PV key indexing lane+64i -> Pp b128
// reads bank-conflict-free (R9's 4*lane pattern was 4x oversubscribed).
// Selection op-for-op identical to R3..R9 (d-ascending fp64 FMA, fp32-cast
// u32 keys, exact-tie fp64 fallback) => same selected set, absmax 2.563e-3.
// ---------------------------------------------------------------------------

#define BB 2
#define NN 2048
#define CC 1024
#define HH 16
#define HD 64
#define KSP 204

typedef _Float16 f16x8v __attribute__((ext_vector_type(8)));

__device__ __forceinline__ unsigned long long mono64(double s) {
  long long bb = __double_as_longlong(s);
  return (unsigned long long)bb ^
         ((bb < 0) ? 0xFFFFFFFFFFFFFFFFull : 0x8000000000000000ull);
}

// ---------------------------------------------------------------------------
// Kernel 1: Q,K projection in fp64. 64x64 tile, 4x4 micro. Cols [0,2048).
// ---------------------------------------------------------------------------
__global__ __launch_bounds__(256) void qk_gemm_f64(
    const float* __restrict__ x, const float* __restrict__ w,
    const float* __restrict__ bqkv, double* __restrict__ Qd,
    double* __restrict__ Kd) {
  __shared__ double As[16][64];  // [k][m]
  __shared__ double Bs[16][64];  // [k][n]
  const int tid = threadIdx.x;
  const int tx = tid & 15, ty = tid >> 4;
  const int colbase = blockIdx.x * 64, rowbase = blockIdx.y * 64;

  double acc[4][4] = {};

  const int sr = tid >> 2, sc = (tid & 3) * 4;
  const int bk = tid >> 4, bn = (tid & 15) * 4;

  for (int kt = 0; kt < 64; ++kt) {
    const int k0 = kt * 16;
    const float4 av = *(const float4*)(x + (size_t)(rowbase + sr) * 1024 + k0 + sc);
    const float4 bv = *(const float4*)(w + (size_t)(k0 + bk) * 3072 + colbase + bn);
    __syncthreads();
    As[sc + 0][sr] = (double)av.x;
    As[sc + 1][sr] = (double)av.y;
    As[sc + 2][sr] = (double)av.z;
    As[sc + 3][sr] = (double)av.w;
    Bs[bk][bn + 0] = (double)bv.x;
    Bs[bk][bn + 1] = (double)bv.y;
    Bs[bk][bn + 2] = (double)bv.z;
    Bs[bk][bn + 3] = (double)bv.w;
    __syncthreads();
#pragma unroll
    for (int k = 0; k < 16; ++k) {
      double a[4], b[4];
#pragma unroll
      for (int i = 0; i < 4; ++i) a[i] = As[k][ty + 16 * i];
#pragma unroll
      for (int j = 0; j < 4; ++j) b[j] = Bs[k][tx + 16 * j];
#pragma unroll
      for (int i = 0; i < 4; ++i)
#pragma unroll
        for (int j = 0; j < 4; ++j) acc[i][j] = fma(a[i], b[j], acc[i][j]);
    }
  }

  const int region = colbase >> 10;  // 0=Q 1=K (uniform per block)
#pragma unroll
  for (int j = 0; j < 4; ++j) {
    const int col = colbase + tx + 16 * j;
    const double bias = (double)bqkv[col];
    const int h = (col & 1023) >> 6, d = col & 63;
#pragma unroll
    for (int i = 0; i < 4; ++i) {
      const int row = rowbase + ty + 16 * i;
      const int b = row >> 11, n = row & 2047;
      const size_t o = ((size_t)((b * HH + h) * HD + d)) * NN + n;
      const double v = acc[i][j] + bias;
      if (region == 0)
        Qd[o] = v * 0.125;
      else
        Kd[o] = v;
    }
  }
}

// ---------------------------------------------------------------------------
// Kernel 1b: V projection in fp32. Cols [2048,3072) of w_qkv.
// ---------------------------------------------------------------------------
__global__ __launch_bounds__(256) void v_gemm_f32(
    const float* __restrict__ x, const float* __restrict__ w,
    const float* __restrict__ bqkv, float* __restrict__ Vf) {
  __shared__ float As[16][64];
  __shared__ float Bs[16][64];
  const int tid = threadIdx.x;
  const int tx = tid & 15, ty = tid >> 4;
  const int colbase = blockIdx.x * 64, rowbase = blockIdx.y * 64;

  float acc[4][4] = {};

  const int sr = tid >> 2, sc = (tid & 3) * 4;
  const int bk = tid >> 4, bn = (tid & 15) * 4;

  for (int kt = 0; kt < 64; ++kt) {
    const int k0 = kt * 16;
    const float4 av = *(const float4*)(x + (size_t)(rowbase + sr) * 1024 + k0 + sc);
    const float4 bv =
        *(const float4*)(w + (size_t)(k0 + bk) * 3072 + 2048 + colbase + bn);
    __syncthreads();
    As[sc + 0][sr] = av.x;
    As[sc + 1][sr] = av.y;
    As[sc + 2][sr] = av.z;
    As[sc + 3][sr] = av.w;
    Bs[bk][bn + 0] = bv.x;
    Bs[bk][bn + 1] = bv.y;
    Bs[bk][bn + 2] = bv.z;
    Bs[bk][bn + 3] = bv.w;
    __syncthreads();
#pragma unroll
    for (int k = 0; k < 16; ++k) {
      float a[4], b[4];
#pragma unroll
      for (int i = 0; i < 4; ++i) a[i] = As[k][ty + 16 * i];
#pragma unroll
      for (int j = 0; j < 4; ++j) b[j] = Bs[k][tx + 16 * j];
#pragma unroll
      for (int i = 0; i < 4; ++i)
#pragma unroll
        for (int j = 0; j < 4; ++j) acc[i][j] = fmaf(a[i], b[j], acc[i][j]);
    }
  }

#pragma unroll
  for (int j = 0; j < 4; ++j) {
    const int col = colbase + tx + 16 * j;
    const float bias = bqkv[2048 + col];
    const int h = col >> 6, d = col & 63;
#pragma unroll
    for (int i = 0; i < 4; ++i) {
      const int row = rowbase + ty + 16 * i;
      const int b = row >> 11, n = row & 2047;
      Vf[((size_t)((b * HH + h) * HD + d)) * NN + n] = acc[i][j] + bias;
    }
  }
}

// ---------------------------------------------------------------------------
// Selection + softmax for one q-row (verified semantics since R4).
// S = 2048 fp64 scores in LDS (re-read each pass). Writes P (f16) key-major
// Pp[key*8 + row]; Z to *Zout.
// ---------------------------------------------------------------------------
__device__ __forceinline__ void do_select(const double* __restrict__ S,
                                          _Float16* __restrict__ Pp,
                                          float* __restrict__ Zout, int lane,
                                          int row) {
  // row max (fp64)
  double mxd = -1.0e300;
#pragma unroll
  for (int i = 0; i < 32; ++i) mxd = fmax(mxd, S[lane + 64 * i]);
#pragma unroll
  for (int m = 1; m < 64; m <<= 1) mxd = fmax(mxd, __shfl_xor(mxd, m, 64));

  // monotone u32 keys from fp32 casts
  unsigned ka[32];
#pragma unroll
  for (int i = 0; i < 32; ++i) {
    const int ib = __float_as_int((float)S[lane + 64 * i]);
    ka[i] = (unsigned)ib ^ ((ib < 0) ? 0xFFFFFFFFu : 0x80000000u);
  }

  // binary search: largest T32 with count(ka >= T32) >= 204
  unsigned T32 = 0;
#pragma unroll 1
  for (int bit = 31; bit >= 0; --bit) {
    const unsigned cand = T32 | (1u << bit);
    int c = 0;
#pragma unroll
    for (int i = 0; i < 32; ++i) c += (ka[i] >= cand) ? 1 : 0;
#pragma unroll
    for (int m = 1; m < 64; m <<= 1) c += __shfl_xor(c, m, 64);
    if (c >= KSP) T32 = cand;
  }

  // exact-tie accounting
  int cpk = 0;
#pragma unroll
  for (int i = 0; i < 32; ++i)
    cpk += (ka[i] > T32) ? (1 << 12) : ((ka[i] == T32) ? 1 : 0);
#pragma unroll
  for (int m = 1; m < 64; m <<= 1) cpk += __shfl_xor(cpk, m, 64);
  const int cgt = cpk >> 12, ceq = cpk & 0xFFF;

  unsigned selmask = 0;
  if (cgt + ceq == KSP) {
#pragma unroll
    for (int i = 0; i < 32; ++i) selmask |= (ka[i] >= T32) ? (1u << i) : 0u;
  } else {  // rare: resolve with exact fp64 keys (re-read from LDS)
    unsigned long long T = 0ull;
#pragma unroll 1
    for (int bit = 63; bit >= 0; --bit) {
      const unsigned long long cand = T | (1ull << bit);
      int c = 0;
#pragma unroll
      for (int i = 0; i < 32; ++i)
        c += (ka[i] == T32 && mono64(S[lane + 64 * i]) >= cand) ? 1 : 0;
#pragma unroll
      for (int m = 1; m < 64; m <<= 1) c += __shfl_xor(c, m, 64);
      if (cgt + c >= KSP) T = cand;
    }
#pragma unroll
    for (int i = 0; i < 32; ++i)
      selmask |= ((ka[i] > T32) ||
                  (ka[i] == T32 && mono64(S[lane + 64 * i]) >= T))
                     ? (1u << i)
                     : 0u;
  }

  // softmax numerators (f16, key-major) + Z
  float z = 0.f;
#pragma unroll
  for (int i = 0; i < 32; ++i) {
    const float p = ((selmask >> i) & 1u)
                        ? __expf((float)(S[lane + 64 * i] - mxd))
                        : 0.0f;
    Pp[(lane + 64 * i) * 8 + row] = (_Float16)p;
    z += p;
  }
#pragma unroll
  for (int m = 1; m < 64; m <<= 1) z += __shfl_xor(z, m, 64);
  if (lane == 0) *Zout = z;
}

// ---------------------------------------------------------------------------
// Kernel 2: fused sparse attention. 1024 thr = 16 waves, 8 q-rows, ~100KB LDS
// (1 block/CU = 16 waves/CU). QK: barrier-free L2 streaming, wave owns 128
// keys -> acc[8][2] (32 VGPR, no spill under the 128 cap). 2 transpose
// phases (4 rows, 64KB TS). PV: wave owns 4 d, keys lane+64i (conflict-free
// b128 P reads).
// ---------------------------------------------------------------------------
__global__ __launch_bounds__(1024, 4) void attn_exact(
    const double* __restrict__ Qd, const double* __restrict__ Kd,
    const float* __restrict__ Vf, float* __restrict__ attnv) {
  __shared__ double TS[4][2048];                 // 64KB: 4 score rows
  __shared__ _Float16 Pp[2048 * 8];              // 32KB: P key-major
  __shared__ __align__(16) double QrowT[64][8];  // 4KB: [d][row]
  __shared__ float Zrow[8];

  const int tid = threadIdx.x;
  const int lane = tid & 63;
  const int w = tid >> 6;  // 0..15

  // XCD-chunked swizzle (bijective, 8192 % 8 == 0)
  const int bid = (int)(blockIdx.x & 7) * 1024 + ((int)blockIdx.x >> 3);
  const int bh = bid >> 8;
  const int n0 = (bid & 255) * 8;

  if (tid < 512) {
    const int d = tid >> 3, r = tid & 7;
    QrowT[d][r] = Qd[((size_t)bh * HD + d) * NN + n0 + r];
  }
  __syncthreads();

  // ---- QK^T: stream K from L2, no barriers.
  //      acc[r][j]: key = 128w + 2*lane + j; fp64 FMA d-ascending. ----
  double acc[8][2];
#pragma unroll
  for (int r = 0; r < 8; ++r) {
    acc[r][0] = 0.0;
    acc[r][1] = 0.0;
  }

  {
    const double* kp = Kd + (size_t)bh * HD * NN + w * 128 + 2 * lane;
#pragma unroll 2
    for (int d = 0; d < 64; ++d) {
      const double2 kv = *(const double2*)(kp + (size_t)d * NN);
      double q[8];
#pragma unroll
      for (int rp = 0; rp < 4; ++rp)
        *(double2*)&q[rp * 2] = *(const double2*)&QrowT[d][rp * 2];
#pragma unroll
      for (int r = 0; r < 8; ++r) {
        acc[r][0] = fma(q[r], kv.x, acc[r][0]);
        acc[r][1] = fma(q[r], kv.y, acc[r][1]);
      }
    }
  }

  // ---- 2 transpose phases (literal P -> acc stays in registers).
  //      Phase P: rows 4P..4P+3 -> TS[0..3]; selected by waves 4P..4P+3. ----
#define TRANS_PHASE(P)                                                        \
  {                                                                           \
    _Pragma("unroll") for (int rr = 0; rr < 4; ++rr) {                        \
      double2 t;                                                              \
      t.x = acc[4 * (P) + rr][0];                                             \
      t.y = acc[4 * (P) + rr][1];                                             \
      *(double2*)&TS[rr][w * 128 + 2 * lane] = t;                             \
    }                                                                         \
    __syncthreads();                                                          \
    if ((w >> 2) == (P))                                                      \
      do_select(&TS[w & 3][0], Pp, &Zrow[4 * (P) + (w & 3)], lane,            \
                4 * (P) + (w & 3));                                           \
    __syncthreads();                                                          \
  }

  TRANS_PHASE(0)
  TRANS_PHASE(1)

  // ---- PV: wave w owns d in [4w, 4w+4); lane's keys = lane + 64*i ----
  const int b2 = bh >> 4, h2 = bh & 15;
  {
    float s[4][8];
#pragma unroll
    for (int d4 = 0; d4 < 4; ++d4)
#pragma unroll
      for (int r = 0; r < 8; ++r) s[d4][r] = 0.f;

    const float* vb = Vf + ((size_t)bh * HD + 4 * w) * NN;
#pragma unroll 2
    for (int i = 0; i < 32; ++i) {
      const int k = lane + 64 * i;
      const f16x8v pk = *(const f16x8v*)&Pp[k * 8];
      float pf[8];
#pragma unroll
      for (int r = 0; r < 8; ++r) pf[r] = (float)pk[r];
      float vv[4];
#pragma unroll
      for (int d4 = 0; d4 < 4; ++d4) vv[d4] = vb[(size_t)d4 * NN + k];
#pragma unroll
      for (int d4 = 0; d4 < 4; ++d4)
#pragma unroll
        for (int r = 0; r < 8; ++r) s[d4][r] = fmaf(pf[r], vv[d4], s[d4][r]);
    }

#pragma unroll
    for (int d4 = 0; d4 < 4; ++d4)
#pragma unroll
      for (int r = 0; r < 8; ++r) {
        float v = s[d4][r];
#pragma unroll
        for (int m = 1; m < 64; m <<= 1) v += __shfl_xor(v, m, 64);
        if (lane == 0)
          attnv[((size_t)(b2 * NN + n0 + r)) * CC + h2 * HD + 4 * w + d4] =
              v / Zrow[r];
      }
  }
}

// ---------------------------------------------------------------------------
// Kernel 3: out = attnv @ w_out + b_out, fp32, 64x64 tile, 4x4 micro.
// ---------------------------------------------------------------------------
__global__ __launch_bounds__(256) void out_gemm_f32(
    const float* __restrict__ A, const float* __restrict__ W,
    const float* __restrict__ bout, float* __restrict__ out) {
  __shared__ float As[16][64];
  __shared__ float Bs[16][64];
  const int tid = threadIdx.x;
  const int tx = tid & 15, ty = tid >> 4;
  const int colbase = blockIdx.x * 64, rowbase = blockIdx.y * 64;

  float acc[4][4] = {};

  const int sr = tid >> 2, sc = (tid & 3) * 4;
  const int bk = tid >> 4, bn = (tid & 15) * 4;

  for (int kt = 0; kt < 64; ++kt) {
    const int k0 = kt * 16;
    const float4 av = *(const float4*)(A + (size_t)(rowbase + sr) * 1024 + k0 + sc);
    const float4 bv = *(const float4*)(W + (size_t)(k0 + bk) * 1024 + colbase + bn);
    __syncthreads();
    As[sc + 0][sr] = av.x;
    As[sc + 1][sr] = av.y;
    As[sc + 2][sr] = av.z;
    As[sc + 3][sr] = av.w;
    Bs[bk][bn + 0] = bv.x;
    Bs[bk][bn + 1] = bv.y;
    Bs[bk][bn + 2] = bv.z;
    Bs[bk][bn + 3] = bv.w;
    __syncthreads();
#pragma unroll
    for (int k = 0; k < 16; ++k) {
      float a[4], b[4];
#pragma unroll
      for (int i = 0; i < 4; ++i) a[i] = As[k][ty + 16 * i];
#pragma unroll
      for (int j = 0; j < 4; ++j) b[j] = Bs[k][tx + 16 * j];
#pragma unroll
      for (int i = 0; i < 4; ++i)
#pragma unroll
        for (int j = 0; j < 4; ++j) acc[i][j] = fmaf(a[i], b[j], acc[i][j]);
    }
  }

#pragma unroll
  for (int j = 0; j < 4; ++j) {
    const int col = colbase + tx + 16 * j;
    const float bias = bout[col];
#pragma unroll
    for (int i = 0; i < 4; ++i) {
      const int row = rowbase + ty + 16 * i;
      out[(size_t)row * CC + col] = acc[i][j] + bias;
    }
  }
}

// ---------------------------------------------------------------------------
extern "C" void kernel_launch(void* const* d_in, const int* in_sizes, int n_in,
                              void* d_out, int out_size, void* d_ws,
                              size_t ws_size, hipStream_t stream) {
  const float* x     = (const float*)d_in[0];
  const float* w_qkv = (const float*)d_in[1];
  const float* b_qkv = (const float*)d_in[2];
  const float* w_out = (const float*)d_in[3];
  const float* b_out = (const float*)d_in[4];
  float* out = (float*)d_out;

  char* ws = (char*)d_ws;
  const size_t SZ_QD = (size_t)BB * HH * HD * NN * 8;  // 33.55 MB
  const size_t SZ_VF = (size_t)BB * HH * HD * NN * 4;  // 16.78 MB
  const size_t SZ_AT = (size_t)4096 * 1024 * 4;        // 16.78 MB

  size_t off = 0;
  double* Qd    = (double*)(ws + off); off += SZ_QD;
  double* Kd    = (double*)(ws + off); off += SZ_QD;
  float*  Vf    = (float*)(ws + off);  off += SZ_VF;
  float*  attnv = (float*)(ws + off);  off += SZ_AT;

  {
    dim3 g(2048 / 64, 4096 / 64);
    qk_gemm_f64<<<g, 256, 0, stream>>>(x, w_qkv, b_qkv, Qd, Kd);
  }
  {
    dim3 g(1024 / 64, 4096 / 64);
    v_gemm_f32<<<g, 256, 0, stream>>>(x, w_qkv, b_qkv, Vf);
  }
  attn_exact<<<BB * HH * (NN / 8), 1024, 0, stream>>>(Qd, Kd, Vf, attnv);
  {
    dim3 g(1024 / 64, 4096 / 64);
    out_gemm_f32<<<g, 256, 0, stream>>>(attnv, w_out, b_out, out);
  }
}

// Round 11
// 1940.534 us; speedup vs baseline: 3.2798x; 1.5146x over previous
//
#include <hip/hip_runtime.h>
#include <cstdint>

// ---------------------------------------------------------------------------
// SparseAttention — R11: attn restructured around the decoded launch_bounds
// semantics (2nd arg ~ min blocks/CU on this compiler: (x,4) => 64-VGPR cap
// => the R9/R10 spills). Now: 512 thr / 8 waves, (512,2) => 128 VGPR budget.
//  - single f32 transpose (all 8 rows, 64KB); all 8 waves select
//    concurrently (zero idle waves); selection uses fp32-cast bits (ka) --
//    IDENTICAL selection set to R3..R10; exact-fp64 tie fallback RECOMPUTES
//    the row from Q(LDS)+K(L2) with the same d-ascending fma chain.
//  - ballot+popcll binary search (no dependent shuffle chains).
//  - Pp (f16) overlays TS after barrier-separated phases; P reconstructed
//    from ka bits (no LDS re-reads). LDS 69.7KB => 2 blocks/CU.
// ---------------------------------------------------------------------------

#define BB 2
#define NN 2048
#define CC 1024
#define HH 16
#define HD 64
#define KSP 204

typedef _Float16 f16x8v __attribute__((ext_vector_type(8)));

__device__ __forceinline__ unsigned long long mono64(double s) {
  long long bb = __double_as_longlong(s);
  return (unsigned long long)bb ^
         ((bb < 0) ? 0xFFFFFFFFFFFFFFFFull : 0x8000000000000000ull);
}

// ---------------------------------------------------------------------------
// Kernel 1: Q,K projection in fp64. 64x64 tile, 4x4 micro. Cols [0,2048).
// ---------------------------------------------------------------------------
__global__ __launch_bounds__(256) void qk_gemm_f64(
    const float* __restrict__ x, const float* __restrict__ w,
    const float* __restrict__ bqkv, double* __restrict__ Qd,
    double* __restrict__ Kd) {
  __shared__ double As[16][64];  // [k][m]
  __shared__ double Bs[16][64];  // [k][n]
  const int tid = threadIdx.x;
  const int tx = tid & 15, ty = tid >> 4;
  const int colbase = blockIdx.x * 64, rowbase = blockIdx.y * 64;

  double acc[4][4] = {};

  const int sr = tid >> 2, sc = (tid & 3) * 4;
  const int bk = tid >> 4, bn = (tid & 15) * 4;

  for (int kt = 0; kt < 64; ++kt) {
    const int k0 = kt * 16;
    const float4 av = *(const float4*)(x + (size_t)(rowbase + sr) * 1024 + k0 + sc);
    const float4 bv = *(const float4*)(w + (size_t)(k0 + bk) * 3072 + colbase + bn);
    __syncthreads();
    As[sc + 0][sr] = (double)av.x;
    As[sc + 1][sr] = (double)av.y;
    As[sc + 2][sr] = (double)av.z;
    As[sc + 3][sr] = (double)av.w;
    Bs[bk][bn + 0] = (double)bv.x;
    Bs[bk][bn + 1] = (double)bv.y;
    Bs[bk][bn + 2] = (double)bv.z;
    Bs[bk][bn + 3] = (double)bv.w;
    __syncthreads();
#pragma unroll
    for (int k = 0; k < 16; ++k) {
      double a[4], b[4];
#pragma unroll
      for (int i = 0; i < 4; ++i) a[i] = As[k][ty + 16 * i];
#pragma unroll
      for (int j = 0; j < 4; ++j) b[j] = Bs[k][tx + 16 * j];
#pragma unroll
      for (int i = 0; i < 4; ++i)
#pragma unroll
        for (int j = 0; j < 4; ++j) acc[i][j] = fma(a[i], b[j], acc[i][j]);
    }
  }

  const int region = colbase >> 10;  // 0=Q 1=K (uniform per block)
#pragma unroll
  for (int j = 0; j < 4; ++j) {
    const int col = colbase + tx + 16 * j;
    const double bias = (double)bqkv[col];
    const int h = (col & 1023) >> 6, d = col & 63;
#pragma unroll
    for (int i = 0; i < 4; ++i) {
      const int row = rowbase + ty + 16 * i;
      const int b = row >> 11, n = row & 2047;
      const size_t o = ((size_t)((b * HH + h) * HD + d)) * NN + n;
      const double v = acc[i][j] + bias;
      if (region == 0)
        Qd[o] = v * 0.125;
      else
        Kd[o] = v;
    }
  }
}

// ---------------------------------------------------------------------------
// Kernel 1b: V projection in fp32. Cols [2048,3072) of w_qkv.
// ---------------------------------------------------------------------------
__global__ __launch_bounds__(256) void v_gemm_f32(
    const float* __restrict__ x, const float* __restrict__ w,
    const float* __restrict__ bqkv, float* __restrict__ Vf) {
  __shared__ float As[16][64];
  __shared__ float Bs[16][64];
  const int tid = threadIdx.x;
  const int tx = tid & 15, ty = tid >> 4;
  const int colbase = blockIdx.x * 64, rowbase = blockIdx.y * 64;

  float acc[4][4] = {};

  const int sr = tid >> 2, sc = (tid & 3) * 4;
  const int bk = tid >> 4, bn = (tid & 15) * 4;

  for (int kt = 0; kt < 64; ++kt) {
    const int k0 = kt * 16;
    const float4 av = *(const float4*)(x + (size_t)(rowbase + sr) * 1024 + k0 + sc);
    const float4 bv =
        *(const float4*)(w + (size_t)(k0 + bk) * 3072 + 2048 + colbase + bn);
    __syncthreads();
    As[sc + 0][sr] = av.x;
    As[sc + 1][sr] = av.y;
    As[sc + 2][sr] = av.z;
    As[sc + 3][sr] = av.w;
    Bs[bk][bn + 0] = bv.x;
    Bs[bk][bn + 1] = bv.y;
    Bs[bk][bn + 2] = bv.z;
    Bs[bk][bn + 3] = bv.w;
    __syncthreads();
#pragma unroll
    for (int k = 0; k < 16; ++k) {
      float a[4], b[4];
#pragma unroll
      for (int i = 0; i < 4; ++i) a[i] = As[k][ty + 16 * i];
#pragma unroll
      for (int j = 0; j < 4; ++j) b[j] = Bs[k][tx + 16 * j];
#pragma unroll
      for (int i = 0; i < 4; ++i)
#pragma unroll
        for (int j = 0; j < 4; ++j) acc[i][j] = fmaf(a[i], b[j], acc[i][j]);
    }
  }

#pragma unroll
  for (int j = 0; j < 4; ++j) {
    const int col = colbase + tx + 16 * j;
    const float bias = bqkv[2048 + col];
    const int h = col >> 6, d = col & 63;
#pragma unroll
    for (int i = 0; i < 4; ++i) {
      const int row = rowbase + ty + 16 * i;
      const int b = row >> 11, n = row & 2047;
      Vf[((size_t)((b * HH + h) * HD + d)) * NN + n] = acc[i][j] + bias;
    }
  }
}

// ---------------------------------------------------------------------------
// Kernel 2: fused sparse attention. 512 thr = 8 waves, 8 q-rows/block.
// Wave w: QK on keys [256w,256w+256) -> f32 transpose -> select own row
// (ballot binary search; fp64 recompute fallback) -> softmax write (Pp
// overlays TS) -> PV on d in [8w,8w+8).
// ---------------------------------------------------------------------------
__global__ __launch_bounds__(512, 2) void attn_exact(
    const double* __restrict__ Qd, const double* __restrict__ Kd,
    const float* __restrict__ Vf, float* __restrict__ attnv) {
  __shared__ __align__(16) float TS32[8][2048];  // 64KB; Pp overlays after B
  __shared__ __align__(16) double QrowT[64][8];  // 4KB: [d][row]
  __shared__ float Zrow[8];

  _Float16* Pp = (_Float16*)&TS32[0][0];  // [key][8 rows] f16, 32KB

  const int tid = threadIdx.x;
  const int lane = tid & 63;
  const int w = tid >> 6;  // 0..7: key-slice role, row role, d-slice role

  // XCD-chunked swizzle (bijective, 8192 % 8 == 0)
  const int bid = (int)(blockIdx.x & 7) * 1024 + ((int)blockIdx.x >> 3);
  const int bh = bid >> 8;
  const int n0 = (bid & 255) * 8;

  const double* Kbh = Kd + (size_t)bh * HD * NN;

  {  // stage Q: 512 values, one per thread
    const int d = tid >> 3, r = tid & 7;
    QrowT[d][r] = Qd[((size_t)bh * HD + d) * NN + n0 + r];
  }
  __syncthreads();

  // ---- Phase A: QK^T, stream K from L2, no barriers.
  //      acc[r][j]: key = 256w + 2*lane + (j&1) + 128*(j>>1); d-ascending. ----
  double acc[8][4];
#pragma unroll
  for (int r = 0; r < 8; ++r)
#pragma unroll
    for (int j = 0; j < 4; ++j) acc[r][j] = 0.0;

  {
    const double* kp = Kbh + w * 256 + 2 * lane;
#pragma unroll 2
    for (int d = 0; d < 64; ++d) {
      const double* kr = kp + (size_t)d * NN;
      const double2 kv0 = *(const double2*)(kr);
      const double2 kv1 = *(const double2*)(kr + 128);
      double q[8];
#pragma unroll
      for (int rp = 0; rp < 4; ++rp)
        *(double2*)&q[rp * 2] = *(const double2*)&QrowT[d][rp * 2];
#pragma unroll
      for (int r = 0; r < 8; ++r) {
        acc[r][0] = fma(q[r], kv0.x, acc[r][0]);
        acc[r][1] = fma(q[r], kv0.y, acc[r][1]);
        acc[r][2] = fma(q[r], kv1.x, acc[r][2]);
        acc[r][3] = fma(q[r], kv1.y, acc[r][3]);
      }
    }
  }

  // ---- Phase B: f32 transpose of ALL 8 rows (float2 writes) ----
#pragma unroll
  for (int r = 0; r < 8; ++r) {
    float2 t0, t1;
    t0.x = (float)acc[r][0];
    t0.y = (float)acc[r][1];
    t1.x = (float)acc[r][2];
    t1.y = (float)acc[r][3];
    *(float2*)&TS32[r][w * 256 + 2 * lane] = t0;
    *(float2*)&TS32[r][w * 256 + 128 + 2 * lane] = t1;
  }
  __syncthreads();

  // ---- Phase C: every wave selects its own row (ballot binary search) ----
  unsigned ka[32];
  unsigned selmask = 0;
  float mxf;
  {
    unsigned kmax = 0;
#pragma unroll
    for (int i = 0; i < 32; ++i) {
      const int ib = __float_as_int(TS32[w][lane + 64 * i]);
      ka[i] = (unsigned)ib ^ ((ib < 0) ? 0xFFFFFFFFu : 0x80000000u);
      kmax = (ka[i] > kmax) ? ka[i] : kmax;
    }
#pragma unroll
    for (int m = 1; m < 64; m <<= 1) {
      const unsigned o = __shfl_xor(kmax, m, 64);
      kmax = (o > kmax) ? o : kmax;
    }
    mxf = __int_as_float(
        (int)((kmax & 0x80000000u) ? (kmax ^ 0x80000000u) : ~kmax));

    unsigned T32 = 0;
#pragma unroll 1
    for (int bit = 31; bit >= 0; --bit) {
      const unsigned cand = T32 | (1u << bit);
      int c = 0;
#pragma unroll
      for (int i = 0; i < 32; ++i) c += __popcll(__ballot(ka[i] >= cand));
      if (c >= KSP) T32 = cand;
    }

    int cgt = 0, ceq = 0;
#pragma unroll
    for (int i = 0; i < 32; ++i) {
      cgt += __popcll(__ballot(ka[i] > T32));
      ceq += __popcll(__ballot(ka[i] == T32));
    }

    if (cgt + ceq == KSP) {  // common: fp32-level selection exact
#pragma unroll
      for (int i = 0; i < 32; ++i)
        selmask |= (ka[i] >= T32) ? (1u << i) : 0u;
    } else {
      // rare: recompute this row's fp64 scores (same d-ascending fma chain
      // as phase A => bit-identical), then 64-bit search among ties.
      double sv[32];
#pragma unroll
      for (int i = 0; i < 32; ++i) sv[i] = 0.0;
#pragma unroll 1
      for (int d = 0; d < 64; ++d) {
        const double qd = QrowT[d][w];
        const double* kr = Kbh + (size_t)d * NN + lane;
#pragma unroll
        for (int i = 0; i < 32; ++i) sv[i] = fma(qd, kr[64 * i], sv[i]);
      }
      unsigned long long T = 0ull;
#pragma unroll 1
      for (int bit = 63; bit >= 0; --bit) {
        const unsigned long long cand = T | (1ull << bit);
        int c = 0;
#pragma unroll
        for (int i = 0; i < 32; ++i)
          c += __popcll(__ballot(ka[i] == T32 && mono64(sv[i]) >= cand));
        if (cgt + c >= KSP) T = cand;
      }
#pragma unroll
      for (int i = 0; i < 32; ++i)
        selmask |= ((ka[i] > T32) || (ka[i] == T32 && mono64(sv[i]) >= T))
                       ? (1u << i)
                       : 0u;
    }
  }
  __syncthreads();  // all TS reads done before Pp overlay

  // ---- Phase D: softmax numerators from ka bits; write Pp (f16) + Z ----
  {
    float z = 0.f;
#pragma unroll
    for (int i = 0; i < 32; ++i) {
      const float f = __int_as_float(
          (int)((ka[i] & 0x80000000u) ? (ka[i] ^ 0x80000000u) : ~ka[i]));
      const float p = ((selmask >> i) & 1u) ? __expf(f - mxf) : 0.0f;
      Pp[(lane + 64 * i) * 8 + w] = (_Float16)p;
      z += p;
    }
#pragma unroll
    for (int m = 1; m < 64; m <<= 1) z += __shfl_xor(z, m, 64);
    if (lane == 0) Zrow[w] = z;
  }
  __syncthreads();

  // ---- Phase E: PV, wave w owns d in [8w,8w+8), two halves of 4 ----
  const int b2 = bh >> 4, h2 = bh & 15;
#define PV_HALF(H)                                                            \
  {                                                                           \
    float s[4][8];                                                            \
    _Pragma("unroll") for (int d4 = 0; d4 < 4; ++d4)                          \
        _Pragma("unroll") for (int r = 0; r < 8; ++r) s[d4][r] = 0.f;         \
    const float* vb = Vf + ((size_t)bh * HD + 8 * w + (H)*4) * NN;            \
    _Pragma("unroll 2") for (int i = 0; i < 32; ++i) {                        \
      const int k = lane + 64 * i;                                            \
      const f16x8v pk = *(const f16x8v*)&Pp[k * 8];                           \
      float pf[8];                                                            \
      _Pragma("unroll") for (int r = 0; r < 8; ++r) pf[r] = (float)pk[r];     \
      float vv[4];                                                            \
      _Pragma("unroll") for (int d4 = 0; d4 < 4; ++d4) vv[d4] =               \
          vb[(size_t)d4 * NN + k];                                            \
      _Pragma("unroll") for (int d4 = 0; d4 < 4; ++d4)                        \
          _Pragma("unroll") for (int r = 0; r < 8; ++r) s[d4][r] =            \
              fmaf(pf[r], vv[d4], s[d4][r]);                                  \
    }                                                                         \
    _Pragma("unroll") for (int d4 = 0; d4 < 4; ++d4)                          \
        _Pragma("unroll") for (int r = 0; r < 8; ++r) {                       \
      float v = s[d4][r];                                                     \
      _Pragma("unroll") for (int m = 1; m < 64; m <<= 1) v +=                 \
          __shfl_xor(v, m, 64);                                               \
      if (lane == 0)                                                          \
        attnv[((size_t)(b2 * NN + n0 + r)) * CC + h2 * HD + 8 * w + (H)*4 +   \
              d4] = v / Zrow[r];                                              \
    }                                                                         \
  }

  PV_HALF(0)
  PV_HALF(1)
}

// ---------------------------------------------------------------------------
// Kernel 3: out = attnv @ w_out + b_out, fp32, 64x64 tile, 4x4 micro.
// ---------------------------------------------------------------------------
__global__ __launch_bounds__(256) void out_gemm_f32(
    const float* __restrict__ A, const float* __restrict__ W,
    const float* __restrict__ bout, float* __restrict__ out) {
  __shared__ float As[16][64];
  __shared__ float Bs[16][64];
  const int tid = threadIdx.x;
  const int tx = tid & 15, ty = tid >> 4;
  const int colbase = blockIdx.x * 64, rowbase = blockIdx.y * 64;

  float acc[4][4] = {};

  const int sr = tid >> 2, sc = (tid & 3) * 4;
  const int bk = tid >> 4, bn = (tid & 15) * 4;

  for (int kt = 0; kt < 64; ++kt) {
    const int k0 = kt * 16;
    const float4 av = *(const float4*)(A + (size_t)(rowbase + sr) * 1024 + k0 + sc);
    const float4 bv = *(const float4*)(W + (size_t)(k0 + bk) * 1024 + colbase + bn);
    __syncthreads();
    As[sc + 0][sr] = av.x;
    As[sc + 1][sr] = av.y;
    As[sc + 2][sr] = av.z;
    As[sc + 3][sr] = av.w;
    Bs[bk][bn + 0] = bv.x;
    Bs[bk][bn + 1] = bv.y;
    Bs[bk][bn + 2] = bv.z;
    Bs[bk][bn + 3] = bv.w;
    __syncthreads();
#pragma unroll
    for (int k = 0; k < 16; ++k) {
      float a[4], b[4];
#pragma unroll
      for (int i = 0; i < 4; ++i) a[i] = As[k][ty + 16 * i];
#pragma unroll
      for (int j = 0; j < 4; ++j) b[j] = Bs[k][tx + 16 * j];
#pragma unroll
      for (int i = 0; i < 4; ++i)
#pragma unroll
        for (int j = 0; j < 4; ++j) acc[i][j] = fmaf(a[i], b[j], acc[i][j]);
    }
  }

#pragma unroll
  for (int j = 0; j < 4; ++j) {
    const int col = colbase + tx + 16 * j;
    const float bias = bout[col];
#pragma unroll
    for (int i = 0; i < 4; ++i) {
      const int row = rowbase + ty + 16 * i;
      out[(size_t)row * CC + col] = acc[i][j] + bias;
    }
  }
}

// ---------------------------------------------------------------------------
extern "C" void kernel_launch(void* const* d_in, const int* in_sizes, int n_in,
                              void* d_out, int out_size, void* d_ws,
                              size_t ws_size, hipStream_t stream) {
  const float* x     = (const float*)d_in[0];
  const float* w_qkv = (const float*)d_in[1];
  const float* b_qkv = (const float*)d_in[2];
  const float* w_out = (const float*)d_in[3];
  const float* b_out = (const float*)d_in[4];
  float* out = (float*)d_out;

  char* ws = (char*)d_ws;
  const size_t SZ_QD = (size_t)BB * HH * HD * NN * 8;  // 33.55 MB
  const size_t SZ_VF = (size_t)BB * HH * HD * NN * 4;  // 16.78 MB
  const size_t SZ_AT = (size_t)4096 * 1024 * 4;        // 16.78 MB

  size_t off = 0;
  double* Qd    = (double*)(ws + off); off += SZ_QD;
  double* Kd    = (double*)(ws + off); off += SZ_QD;
  float*  Vf    = (float*)(ws + off);  off += SZ_VF;
  float*  attnv = (float*)(ws + off);  off += SZ_AT;

  {
    dim3 g(2048 / 64, 4096 / 64);
    qk_gemm_f64<<<g, 256, 0, stream>>>(x, w_qkv, b_qkv, Qd, Kd);
  }
  {
    dim3 g(1024 / 64, 4096 / 64);
    v_gemm_f32<<<g, 256, 0, stream>>>(x, w_qkv, b_qkv, Vf);
  }
  attn_exact<<<BB * HH * (NN / 8), 512, 0, stream>>>(Qd, Kd, Vf, attnv);
  {
    dim3 g(1024 / 64, 4096 / 64);
    out_gemm_f32<<<g, 256, 0, stream>>>(attnv, w_out, b_out, out);
  }
}